// Round 2
// baseline (100.088 us; speedup 1.0000x reference)
//
#include <hip/hip_runtime.h>
#include <hip/hip_bf16.h>
#include <math.h>

// Problem constants (BayesPredictor): inputs [B,D] f32, alphas [B] f32, data [N,D] f32
#define BB 32
#define DD 128
#define NN 32768

#define NB 256            // kernel-1 blocks
#define ROWS_PB (NN/NB)   // 128 rows per block
#define TILE 32           // rows per LDS tile
#define NT (ROWS_PB/TILE) // 4 tiles per block
#define LDSW 33           // float4 per row in LDS (132 floats, +4 pad words: bank spread)
#define WS_STRIDE 132     // floats per (block,b) partial: m, s, pad, pad, acc[128]

// ---------------- kernel 1: streaming pass over data, per-block online softmax ----------------
__global__ __launch_bounds__(256) void bayes_k1(
    const float* __restrict__ inputs, const float* __restrict__ alphas,
    const float* __restrict__ data, float* __restrict__ ws)
{
    __shared__ float4 buf[2][TILE * LDSW];   // 2 * 32 * 33 * 16B = 33792 B

    const int tid  = threadIdx.x;
    const int lane = tid & 63;
    const int wv   = tid >> 6;        // wave 0..3
    const int b    = lane >> 1;       // batch handled by this lane-pair
    const int h    = lane & 1;        // which 64-float half of D

    const int bid = blockIdx.x;

    // per-b constants
    const float alpha = alphas[b];
    const float sa    = sqrtf(alpha);
    const float var   = 1.0f - alpha;
    const float c1    = sa / var;
    const float c2    = 0.5f * alpha / var;
    (void)sa;

    // inputs half-row -> registers (64 floats)
    float4 in4[16];
    {
        const float4* ig = (const float4*)(inputs + b * DD + h * 64);
        #pragma unroll
        for (int j = 0; j < 16; ++j) in4[j] = ig[j];
    }

    // online softmax state (deferred max, threshold 10)
    float m = -INFINITY, s = 0.0f;
    float4 acc[16];
    #pragma unroll
    for (int j = 0; j < 16; ++j) acc[j] = make_float4(0.f, 0.f, 0.f, 0.f);

    const float4* g4 = (const float4*)(data) + (size_t)bid * (ROWS_PB * DD / 4);

    // prologue: stage tile 0
    {
        float4 r0[4];
        #pragma unroll
        for (int k = 0; k < 4; ++k) r0[k] = g4[k * 256 + tid];
        #pragma unroll
        for (int k = 0; k < 4; ++k) {
            const int f  = k * 256 + tid;      // tile float4 index
            const int rr = f >> 5, cc = f & 31;
            buf[0][rr * LDSW + cc] = r0[k];
        }
    }
    __syncthreads();

    for (int t = 0; t < NT; ++t) {
        const int cur = t & 1;

        // T14 async-split: issue next tile's global loads now, write to LDS after compute
        float4 rs[4];
        if (t + 1 < NT) {
            #pragma unroll
            for (int k = 0; k < 4; ++k) rs[k] = g4[(t + 1) * 1024 + k * 256 + tid];
        }

        // wave-local row norms: this wave's 8 rows, 8 lanes per row
        const int rg = wv * 8 + (lane >> 3);  // row in tile
        const int pp = lane & 7;
        float nn = 0.0f;
        #pragma unroll
        for (int j = 0; j < 4; ++j) {
            const float4 d = buf[cur][rg * LDSW + pp * 4 + j];
            nn = fmaf(d.x, d.x, nn); nn = fmaf(d.y, d.y, nn);
            nn = fmaf(d.z, d.z, nn); nn = fmaf(d.w, d.w, nn);
        }
        nn += __shfl_xor(nn, 1);
        nn += __shfl_xor(nn, 2);
        nn += __shfl_xor(nn, 4);   // lane group (lane>>3)==g holds nn of row wv*8+g

        // process the wave's 8 rows
        #pragma unroll
        for (int i = 0; i < 8; ++i) {
            const int r = wv * 8 + i;
            const float4* rb = &buf[cur][r * LDSW + h * 16];

            float4 d4;
            float4 dot4 = make_float4(0.f, 0.f, 0.f, 0.f);
            #pragma unroll
            for (int j = 0; j < 16; ++j) {
                d4 = rb[j];
                dot4.x = fmaf(in4[j].x, d4.x, dot4.x);
                dot4.y = fmaf(in4[j].y, d4.y, dot4.y);
                dot4.z = fmaf(in4[j].z, d4.z, dot4.z);
                dot4.w = fmaf(in4[j].w, d4.w, dot4.w);
            }
            float dot = (dot4.x + dot4.y) + (dot4.z + dot4.w);
            dot += __shfl_xor(dot, 1);          // pair-combine halves -> full dot on both lanes

            const float nr = __shfl(nn, i << 3);
            const float logit = c1 * dot - c2 * nr;

            float p = logit - m;
            if (p > 10.0f) {                    // deferred rescale (rare)
                const float sc = __expf(-p);    // exp(m - logit); first row: exp(-inf)=0
                s *= sc;
                #pragma unroll
                for (int j = 0; j < 16; ++j) {
                    acc[j].x *= sc; acc[j].y *= sc; acc[j].z *= sc; acc[j].w *= sc;
                }
                m = logit; p = 0.0f;
            }
            const float wgt = __expf(p);
            s += wgt;
            #pragma unroll
            for (int j = 0; j < 16; ++j) {
                const float4 d = rb[j];
                acc[j].x = fmaf(wgt, d.x, acc[j].x);
                acc[j].y = fmaf(wgt, d.y, acc[j].y);
                acc[j].z = fmaf(wgt, d.z, acc[j].z);
                acc[j].w = fmaf(wgt, d.w, acc[j].w);
            }
        }

        // write next tile to the other buffer (stalls on vmcnt AFTER compute)
        if (t + 1 < NT) {
            #pragma unroll
            for (int k = 0; k < 4; ++k) {
                const int f  = k * 256 + tid;
                const int rr = f >> 5, cc = f & 31;
                buf[cur ^ 1][rr * LDSW + cc] = rs[k];
            }
        }
        __syncthreads();
    }

    // ---------------- epilogue: merge 4 waves' partials via LDS tree ----------------
    float* red = (float*)&buf[0][0];   // two regions of 32*132 floats (16896 B each)

    // round 1: waves 1,3 publish
    if (wv & 1) {
        float* regp = red + (wv >> 1) * (32 * WS_STRIDE) + b * WS_STRIDE;
        if (h == 0) { regp[0] = m; regp[1] = s; }
        float4* ra = (float4*)(regp + 4) + h * 16;
        #pragma unroll
        for (int j = 0; j < 16; ++j) ra[j] = acc[j];
    }
    __syncthreads();
    // waves 0,2 merge
    if (!(wv & 1)) {
        const float* regp = red + (wv >> 1) * (32 * WS_STRIDE) + b * WS_STRIDE;
        const float mo = regp[0], so = regp[1];
        const float M  = fmaxf(m, mo);
        const float e0 = __expf(m - M), e1 = __expf(mo - M);
        s = s * e0 + so * e1;
        const float4* ra = (const float4*)(regp + 4) + h * 16;
        #pragma unroll
        for (int j = 0; j < 16; ++j) {
            const float4 d = ra[j];
            acc[j].x = acc[j].x * e0 + e1 * d.x;
            acc[j].y = acc[j].y * e0 + e1 * d.y;
            acc[j].z = acc[j].z * e0 + e1 * d.z;
            acc[j].w = acc[j].w * e0 + e1 * d.w;
        }
        m = M;
    }
    __syncthreads();
    // round 2: wave 2 publishes into region 0
    if (wv == 2) {
        float* regp = red + b * WS_STRIDE;
        if (h == 0) { regp[0] = m; regp[1] = s; }
        float4* ra = (float4*)(regp + 4) + h * 16;
        #pragma unroll
        for (int j = 0; j < 16; ++j) ra[j] = acc[j];
    }
    __syncthreads();
    // wave 0 final merge + global write
    if (wv == 0) {
        const float* regp = red + b * WS_STRIDE;
        const float mo = regp[0], so = regp[1];
        const float M  = fmaxf(m, mo);
        const float e0 = __expf(m - M), e1 = __expf(mo - M);
        s = s * e0 + so * e1;
        const float4* ra = (const float4*)(regp + 4) + h * 16;
        #pragma unroll
        for (int j = 0; j < 16; ++j) {
            const float4 d = ra[j];
            acc[j].x = acc[j].x * e0 + e1 * d.x;
            acc[j].y = acc[j].y * e0 + e1 * d.y;
            acc[j].z = acc[j].z * e0 + e1 * d.z;
            acc[j].w = acc[j].w * e0 + e1 * d.w;
        }
        m = M;

        float* wsp = ws + ((size_t)bid * BB + b) * WS_STRIDE;
        if (h == 0) { wsp[0] = m; wsp[1] = s; }
        float4* wa = (float4*)(wsp + 4) + h * 16;
        #pragma unroll
        for (int j = 0; j < 16; ++j) wa[j] = acc[j];
    }
}

// ---------------- kernel 2: cross-block softmax combine + output ----------------
__global__ __launch_bounds__(256) void bayes_k2(
    const float* __restrict__ inputs, const float* __restrict__ alphas,
    const float* __restrict__ ws, float* __restrict__ out)
{
    const int b  = blockIdx.x >> 2;   // 0..31
    const int dq = blockIdx.x & 3;    // d-quarter
    const int tid = threadIdx.x;

    __shared__ float e_s[NB];
    __shared__ float red_s[16];
    __shared__ float part[8][32];

    // per-partial m,s (one per thread; NB==256 threads)
    const float* base = ws + (size_t)b * WS_STRIDE;
    const float mi = base[(size_t)tid * (BB * WS_STRIDE)];
    const float si = base[(size_t)tid * (BB * WS_STRIDE) + 1];

    // global max M over 256 partials
    float mm = mi;
    #pragma unroll
    for (int off = 1; off <= 32; off <<= 1) mm = fmaxf(mm, __shfl_xor(mm, off));
    if ((tid & 63) == 0) red_s[tid >> 6] = mm;
    __syncthreads();
    const float M = fmaxf(fmaxf(red_s[0], red_s[1]), fmaxf(red_s[2], red_s[3]));

    const float ei = __expf(mi - M);
    e_s[tid] = ei;
    float ss = si * ei;
    #pragma unroll
    for (int off = 1; off <= 32; off <<= 1) ss += __shfl_xor(ss, off);
    if ((tid & 63) == 0) red_s[8 + (tid >> 6)] = ss;
    __syncthreads();
    const float S = (red_s[8] + red_s[9]) + (red_s[10] + red_s[11]);

    // x0 slice: 32 d-values, 8-way split over partials
    const int dd = tid & 31, ii = tid >> 5;
    const int d  = dq * 32 + dd;
    float x = 0.0f;
    #pragma unroll 4
    for (int k = 0; k < 32; ++k) {
        const int i = ii + k * 8;
        x = fmaf(e_s[i], ws[((size_t)i * BB + b) * WS_STRIDE + 4 + d], x);
    }
    part[ii][dd] = x;
    __syncthreads();

    if (tid < 32) {
        float x0 = 0.0f;
        #pragma unroll
        for (int q = 0; q < 8; ++q) x0 += part[q][tid];
        x0 /= S;
        const float alpha = alphas[b];
        const float sa  = sqrtf(alpha);
        const float var = 1.0f - alpha;
        const int dout  = dq * 32 + tid;
        out[b * DD + dout] = (inputs[b * DD + dout] - sa * x0) / sqrtf(var);
    }
}

extern "C" void kernel_launch(void* const* d_in, const int* in_sizes, int n_in,
                              void* d_out, int out_size, void* d_ws, size_t ws_size,
                              hipStream_t stream)
{
    const float* inputs = (const float*)d_in[0];   // [B,D]
    const float* alphas = (const float*)d_in[1];   // [B]
    const float* data   = (const float*)d_in[2];   // [N,D]
    float* out = (float*)d_out;
    float* ws  = (float*)d_ws;                     // needs NB*B*132*4 = 4.33 MB

    bayes_k1<<<NB, 256, 0, stream>>>(inputs, alphas, data, ws);
    bayes_k2<<<BB * 4, 256, 0, stream>>>(inputs, alphas, ws, out);
}